// Round 7
// baseline (443.002 us; speedup 1.0000x reference)
//
#include <hip/hip_runtime.h>
#include <math.h>

// ---------------------------------------------------------------------------
// ADSAGE: 2x SAGEConv (mean aggr) + softmax + GCNConv, fp32.
// Aggregate-after-GEMM (mean is linear). GEMMs on matrix cores via
// split-bf16 (3-term). CSR via 2-pass radix sort by dst. Gathers are
// feature-chunk sharded (16 floats = 64B per chunk) with chunk pinned to an
// XCD via blockIdx%8 so each chunk's 3.2MB working set stays in one 4MB L2.
// Pipeline:
//   p,q = x @ [W1l|W1r]                          MFMA GEMM K=128
//   h1  = relu(mean(p) + q + b1l)                sharded gather (8 chunks)
//   r,s = h1 @ [W2l|W2r]                         MFMA GEMM K=128
//   v   = mean(r) + s + b2l                      sharded gather (4 chunks)
//   h2  = softmax(v)                             wave/node pass
//   t'  = (h2 @ Wg) * dinv[row]                  MFMA GEMM K=64 + epilogue
//   out = dinv*(sum_j t'[j] + t'[i]) + bg        sharded gather (4 chunks)
// ---------------------------------------------------------------------------

typedef __attribute__((ext_vector_type(8))) short bf16x8;
typedef __attribute__((ext_vector_type(4))) float f32x4;

__device__ inline unsigned short f32_bf16_hi(float f) {
    unsigned int u = __builtin_bit_cast(unsigned int, f);
    u = (u + 0x7FFFu + ((u >> 16) & 1u)) >> 16;
    return (unsigned short)u;
}
__device__ inline float bf16_to_f32(unsigned short h) {
    unsigned int u = ((unsigned int)h) << 16;
    return __builtin_bit_cast(float, u);
}

// ----------------------- radix CSR build (by dst) --------------------------
__global__ void count_kernel(const int* __restrict__ dst, int* __restrict__ off,
                             int E, int NB, int BK) {
    __shared__ int hist[256];
    int t = threadIdx.x;
    hist[t] = 0;
    __syncthreads();
    int base = blockIdx.x * 8192;
    for (int i = t; i < 8192; i += 256) {
        int e = base + i;
        if (e < E) atomicAdd(&hist[dst[e] >> 8], 1);
    }
    __syncthreads();
    if (t < BK) off[1 + t * NB + blockIdx.x] = hist[t];
    if (blockIdx.x == 0 && t == 0) off[0] = 0;
}

__global__ void scan_reduce_kernel(const int* __restrict__ data, int* __restrict__ bsum, int n) {
    __shared__ int red[256];
    int t = threadIdx.x;
    int base = blockIdx.x * 2048 + t * 8;
    int s = 0;
    if (base + 8 <= n) {
        int4 a = *(const int4*)(data + base);
        int4 b = *(const int4*)(data + base + 4);
        s = a.x + a.y + a.z + a.w + b.x + b.y + b.z + b.w;
    } else {
        for (int i = 0; i < 8; ++i)
            if (base + i < n) s += data[base + i];
    }
    red[t] = s;
    __syncthreads();
    for (int off = 128; off > 0; off >>= 1) {
        if (t < off) red[t] += red[t + off];
        __syncthreads();
    }
    if (t == 0) bsum[blockIdx.x] = red[0];
}

__global__ void scan_offsets_kernel(int* __restrict__ bsum, int B) {
    if (threadIdx.x == 0 && blockIdx.x == 0) {
        int run = 0;
        for (int i = 0; i < B; ++i) { int v = bsum[i]; bsum[i] = run; run += v; }
    }
}

__global__ void scan_final_kernel(int* __restrict__ data, const int* __restrict__ bsum, int n) {
    __shared__ int tsum[256];
    int t = threadIdx.x;
    int base = blockIdx.x * 2048 + t * 8;
    int v[8];
    int s = 0;
#pragma unroll
    for (int i = 0; i < 8; ++i) {
        v[i] = (base + i < n) ? data[base + i] : 0;
        s += v[i];
    }
    tsum[t] = s;
    for (int off = 1; off < 256; off <<= 1) {
        __syncthreads();
        int u = (t >= off) ? tsum[t - off] : 0;
        __syncthreads();
        tsum[t] += u;
    }
    __syncthreads();
    int run = bsum[blockIdx.x] + tsum[t] - s;
#pragma unroll
    for (int i = 0; i < 8; ++i) {
        run += v[i];
        if (base + i < n) data[base + i] = run;
    }
}

__global__ void partition_kernel(const int* __restrict__ src, const int* __restrict__ dst,
                                 const int* __restrict__ off, unsigned* __restrict__ ebuf,
                                 int E, int NB, int BK) {
    __shared__ int cur[256];
    int t = threadIdx.x;
    if (t < BK) cur[t] = off[t * NB + blockIdx.x];
    __syncthreads();
    int base = blockIdx.x * 8192;
    for (int i = t; i < 8192; i += 256) {
        int e = base + i;
        if (e < E) {
            int d = dst[e];
            int pos = atomicAdd(&cur[d >> 8], 1);
            ebuf[pos] = ((unsigned)src[e] << 8) | (unsigned)(d & 255);
        }
    }
}

__global__ void finalize_kernel(const unsigned* __restrict__ ebuf, const int* __restrict__ off,
                                int* __restrict__ col, int* __restrict__ rowptr,
                                float* __restrict__ dinv, int N, int NB, int E) {
    __shared__ int hist[256], scn[256], cur[256];
    int b = blockIdx.x, t = threadIdx.x;
    int base = off[b * NB];
    int end  = off[(b + 1) * NB];
    int M = end - base;
    hist[t] = 0;
    __syncthreads();
    for (int i = t; i < M; i += 256) atomicAdd(&hist[ebuf[base + i] & 255u], 1);
    __syncthreads();
    scn[t] = hist[t];
    for (int o = 1; o < 256; o <<= 1) {
        __syncthreads();
        int u = (t >= o) ? scn[t - o] : 0;
        __syncthreads();
        scn[t] += u;
    }
    __syncthreads();
    int excl = scn[t] - hist[t];
    int node = b * 256 + t;
    if (node < N) {
        rowptr[node] = base + excl;
        dinv[node] = rsqrtf((float)(hist[t] + 1));
    }
    if (b == 0 && t == 0) rowptr[N] = E;
    cur[t] = base + excl;
    __syncthreads();
    for (int i = t; i < M; i += 256) {
        unsigned w = ebuf[base + i];
        int pos = atomicAdd(&cur[w & 255u], 1);
        col[pos] = (int)(w >> 8);
    }
}

// -------------------------- weight pre-pack --------------------------------
__global__ void packw_kernel(const float* __restrict__ W1l, const float* __restrict__ W1r,
                             const float* __restrict__ W2l, const float* __restrict__ W2r,
                             const float* __restrict__ Wg,
                             unsigned short* __restrict__ p1h, unsigned short* __restrict__ p1l,
                             unsigned short* __restrict__ p2h, unsigned short* __restrict__ p2l,
                             unsigned short* __restrict__ p3h, unsigned short* __restrict__ p3l) {
    int which = blockIdx.y;
    const float* W;
    unsigned short *hi, *lo;
    int K, Mp, colOff, T;
    if (which == 0)      { W = W1l; hi = p1h; lo = p1l; K = 128; Mp = 128; colOff = 0;   T = 16; }
    else if (which == 1) { W = W1r; hi = p1h; lo = p1l; K = 128; Mp = 128; colOff = 128; T = 16; }
    else if (which == 2) { W = W2l; hi = p2h; lo = p2l; K = 128; Mp = 64;  colOff = 0;   T = 8;  }
    else if (which == 3) { W = W2r; hi = p2h; lo = p2l; K = 128; Mp = 64;  colOff = 64;  T = 8;  }
    else                 { W = Wg;  hi = p3h; lo = p3l; K = 64;  Mp = 64;  colOff = 0;   T = 4;  }
    int idx = blockIdx.x * blockDim.x + threadIdx.x;
    if (idx >= K * Mp) return;
    int k = idx / Mp, m = idx % Mp;
    float w = W[(size_t)k * Mp + m];
    int colI = colOff + m;
    int s = k >> 5, kk = k & 31, qq = kk >> 3, j = kk & 7;
    int tt = colI >> 4, n = colI & 15;
    int lane = qq * 16 + n;
    size_t pos = ((size_t)(s * T + tt) * 64 + lane) * 8 + j;
    unsigned short h = f32_bf16_hi(w);
    hi[pos] = h;
    lo[pos] = f32_bf16_hi(w - bf16_to_f32(h));
}

// --------------------------- MFMA GEMM -------------------------------------
// out = A[N,K] @ Wpacked[K,M]. SPLIT: cols [0,M/2)->outA, [M/2,M)->outB.
// rowScale (optional): multiply output row by rowScale[row].
template <int K, int M, bool SPLIT>
__launch_bounds__(256)
__global__ void gemm_mfma_kernel(const float* __restrict__ A,
                                 const unsigned short* __restrict__ Whi,
                                 const unsigned short* __restrict__ Wlo,
                                 float* __restrict__ outA, float* __restrict__ outB,
                                 const float* __restrict__ rowScale, int N) {
    constexpr int S = K / 32, T = M / 16, H = M / 2;
    const int lane = threadIdx.x & 63;
    const int wave = threadIdx.x >> 6;
    const int m = lane & 15, q = lane >> 4;
    const int row0 = blockIdx.x * 64 + wave * 16;
    int arow = row0 + m;
    if (arow >= N) arow = N - 1;       // clamp: only pollutes rows we don't store
    const float* ap = A + (size_t)arow * K + q * 8;

    f32x4 acc[T];
#pragma unroll
    for (int t = 0; t < T; ++t) acc[t] = (f32x4)(0.f);

#pragma unroll
    for (int s = 0; s < S; ++s) {
        float av[8];
        *(float4*)(av)     = *(const float4*)(ap + s * 32);
        *(float4*)(av + 4) = *(const float4*)(ap + s * 32 + 4);
        bf16x8 ahi, alo;
#pragma unroll
        for (int i = 0; i < 8; ++i) {
            unsigned short h = f32_bf16_hi(av[i]);
            ahi[i] = (short)h;
            alo[i] = (short)f32_bf16_hi(av[i] - bf16_to_f32(h));
        }
        const int base = s * T * 64 + lane;
        const bf16x8* whp = (const bf16x8*)Whi;
        const bf16x8* wlp = (const bf16x8*)Wlo;
#pragma unroll
        for (int t = 0; t < T; ++t) {
            bf16x8 wh = whp[base + t * 64];
            bf16x8 wl = wlp[base + t * 64];
            acc[t] = __builtin_amdgcn_mfma_f32_16x16x32_bf16(ahi, wh, acc[t], 0, 0, 0);
            acc[t] = __builtin_amdgcn_mfma_f32_16x16x32_bf16(alo, wh, acc[t], 0, 0, 0);
            acc[t] = __builtin_amdgcn_mfma_f32_16x16x32_bf16(ahi, wl, acc[t], 0, 0, 0);
        }
    }

#pragma unroll
    for (int r = 0; r < 4; ++r) {
        int row = row0 + q * 4 + r;
        if (row < N) {
            float sc = rowScale ? rowScale[row] : 1.0f;
#pragma unroll
            for (int t = 0; t < T; ++t) {
                int c = t * 16 + m;
                float v = acc[t][r] * sc;
                if (!SPLIT) {
                    outA[(size_t)row * M + c] = v;
                } else if (c < H) {
                    outA[(size_t)row * H + c] = v;
                } else {
                    outB[(size_t)row * H + (c - H)] = v;
                }
            }
        }
    }
}

// ----------------------- sharded gathers -----------------------------------
// Wave processes NPW nodes for one 16-float chunk; 16 edges in flight
// (4 lanes x float4 per edge); cross-group shfl_xor reduction.
// CHUNKS: number of chunks (feature dim = CHUNKS*16). chunk = blockIdx%CHUNKS
// pins chunk to an XCD subset (XCD = blockIdx%8 round robin).

// h1 = relu(mean(p) + q + b1l); p,q lead dim 128, 8 chunks
__global__ void agg1_sharded_kernel(const float* __restrict__ p, const float* __restrict__ q,
                                    const int* __restrict__ rowptr, const int* __restrict__ col,
                                    const float* __restrict__ b1l,
                                    float* __restrict__ h1, int N) {
    const int chunk = blockIdx.x & 7;
    const int lane = threadIdx.x & 63;
    const int g = lane >> 2, fl = lane & 3;
    const int fo = chunk * 16 + fl * 4;
    int nb = (blockIdx.x >> 3) * 16 + (threadIdx.x >> 6) * 4;
#pragma unroll
    for (int nn = 0; nn < 4; ++nn) {
        int node = nb + nn;
        if (node >= N) break;
        int s = rowptr[node], e = rowptr[node + 1];
        float4 acc = make_float4(0.f, 0.f, 0.f, 0.f);
        for (int base = s; base < e; base += 16) {
            int idx = base + g;
            if (idx < e) {
                int j = col[idx];
                float4 v = *(const float4*)(p + (size_t)j * 128 + fo);
                acc.x += v.x; acc.y += v.y; acc.z += v.z; acc.w += v.w;
            }
        }
#pragma unroll
        for (int o = 4; o < 64; o <<= 1) {
            acc.x += __shfl_xor(acc.x, o, 64);
            acc.y += __shfl_xor(acc.y, o, 64);
            acc.z += __shfl_xor(acc.z, o, 64);
            acc.w += __shfl_xor(acc.w, o, 64);
        }
        if (lane < 4) {
            float inv = 1.0f / fmaxf((float)(e - s), 1.0f);
            int f = chunk * 16 + lane * 4;
            float4 qv = *(const float4*)(q + (size_t)node * 128 + f);
            float4 bv = *(const float4*)(b1l + f);
            float4 r;
            r.x = fmaxf(acc.x * inv + qv.x + bv.x, 0.f);
            r.y = fmaxf(acc.y * inv + qv.y + bv.y, 0.f);
            r.z = fmaxf(acc.z * inv + qv.z + bv.z, 0.f);
            r.w = fmaxf(acc.w * inv + qv.w + bv.w, 0.f);
            *(float4*)(h1 + (size_t)node * 128 + f) = r;
        }
    }
}

// v = mean(r) + s + b2l (pre-softmax); r,s lead dim 64, 4 chunks
__global__ void agg2_sharded_kernel(const float* __restrict__ rr, const float* __restrict__ ss,
                                    const int* __restrict__ rowptr, const int* __restrict__ col,
                                    const float* __restrict__ b2l,
                                    float* __restrict__ h2, int N) {
    const int chunk = blockIdx.x & 3;
    const int lane = threadIdx.x & 63;
    const int g = lane >> 2, fl = lane & 3;
    const int fo = chunk * 16 + fl * 4;
    int nb = (blockIdx.x >> 2) * 16 + (threadIdx.x >> 6) * 4;
#pragma unroll
    for (int nn = 0; nn < 4; ++nn) {
        int node = nb + nn;
        if (node >= N) break;
        int s = rowptr[node], e = rowptr[node + 1];
        float4 acc = make_float4(0.f, 0.f, 0.f, 0.f);
        for (int base = s; base < e; base += 16) {
            int idx = base + g;
            if (idx < e) {
                int j = col[idx];
                float4 v = *(const float4*)(rr + (size_t)j * 64 + fo);
                acc.x += v.x; acc.y += v.y; acc.z += v.z; acc.w += v.w;
            }
        }
#pragma unroll
        for (int o = 4; o < 64; o <<= 1) {
            acc.x += __shfl_xor(acc.x, o, 64);
            acc.y += __shfl_xor(acc.y, o, 64);
            acc.z += __shfl_xor(acc.z, o, 64);
            acc.w += __shfl_xor(acc.w, o, 64);
        }
        if (lane < 4) {
            float inv = 1.0f / fmaxf((float)(e - s), 1.0f);
            int f = chunk * 16 + lane * 4;
            float4 sv = *(const float4*)(ss + (size_t)node * 64 + f);
            float4 bv = *(const float4*)(b2l + f);
            float4 r;
            r.x = acc.x * inv + sv.x + bv.x;
            r.y = acc.y * inv + sv.y + bv.y;
            r.z = acc.z * inv + sv.z + bv.z;
            r.w = acc.w * inv + sv.w + bv.w;
            *(float4*)(h2 + (size_t)node * 64 + f) = r;
        }
    }
}

// in-place row softmax over 64 features, wave per node
__global__ void softmax64_kernel(float* __restrict__ h, int N) {
    int row = blockIdx.x * 4 + (threadIdx.x >> 6);
    if (row >= N) return;
    int lane = threadIdx.x & 63;
    float v = h[(size_t)row * 64 + lane];
    float m = v;
#pragma unroll
    for (int o = 32; o > 0; o >>= 1) m = fmaxf(m, __shfl_xor(m, o, 64));
    float ex = expf(v - m);
    float s = ex;
#pragma unroll
    for (int o = 32; o > 0; o >>= 1) s += __shfl_xor(s, o, 64);
    h[(size_t)row * 64 + lane] = ex / s;
}

// out = dinv[i]*(sum_j tp[j] + tp[i]) + bg, where tp = t*dinv (gemm3 epilogue)
__global__ void gcn_sharded_kernel(const float* __restrict__ tp,
                                   const int* __restrict__ rowptr, const int* __restrict__ col,
                                   const float* __restrict__ dinv, const float* __restrict__ bg,
                                   float* __restrict__ out, int N) {
    const int chunk = blockIdx.x & 3;
    const int lane = threadIdx.x & 63;
    const int g = lane >> 2, fl = lane & 3;
    const int fo = chunk * 16 + fl * 4;
    int nb = (blockIdx.x >> 2) * 16 + (threadIdx.x >> 6) * 4;
#pragma unroll
    for (int nn = 0; nn < 4; ++nn) {
        int node = nb + nn;
        if (node >= N) break;
        int s = rowptr[node], e = rowptr[node + 1];
        float4 acc = make_float4(0.f, 0.f, 0.f, 0.f);
        for (int base = s; base < e; base += 16) {
            int idx = base + g;
            if (idx < e) {
                int j = col[idx];
                float4 v = *(const float4*)(tp + (size_t)j * 64 + fo);
                acc.x += v.x; acc.y += v.y; acc.z += v.z; acc.w += v.w;
            }
        }
#pragma unroll
        for (int o = 4; o < 64; o <<= 1) {
            acc.x += __shfl_xor(acc.x, o, 64);
            acc.y += __shfl_xor(acc.y, o, 64);
            acc.z += __shfl_xor(acc.z, o, 64);
            acc.w += __shfl_xor(acc.w, o, 64);
        }
        if (lane < 4) {
            float di = dinv[node];
            int f = chunk * 16 + lane * 4;
            float4 self = *(const float4*)(tp + (size_t)node * 64 + f);
            float4 bv = *(const float4*)(bg + f);
            float4 r;
            r.x = (acc.x + self.x) * di + bv.x;
            r.y = (acc.y + self.y) * di + bv.y;
            r.z = (acc.z + self.z) * di + bv.z;
            r.w = (acc.w + self.w) * di + bv.w;
            *(float4*)(out + (size_t)node * 64 + f) = r;
        }
    }
}

extern "C" void kernel_launch(void* const* d_in, const int* in_sizes, int n_in,
                              void* d_out, int out_size, void* d_ws, size_t ws_size,
                              hipStream_t stream) {
    const float* x = (const float*)d_in[0];
    const int* ei = (const int*)d_in[1];    // int32 per harness conversion
    const float* W1l = (const float*)d_in[2];
    const float* b1l = (const float*)d_in[3];
    const float* W1r = (const float*)d_in[4];
    const float* W2l = (const float*)d_in[5];
    const float* b2l = (const float*)d_in[6];
    const float* W2r = (const float*)d_in[7];
    const float* Wg  = (const float*)d_in[8];
    const float* bg  = (const float*)d_in[9];

    const int N = in_sizes[0] / 128;
    const int E = in_sizes[1] / 2;
    const int* srcp = ei;
    const int* dstp = ei + E;

    const int NB = (E + 8191) / 8192;       // partition blocks
    const int BK = (N + 255) >> 8;          // dst buckets
    const int len = BK * NB;

    // workspace layout
    float* ws = (float*)d_ws;
    float* p    = ws;                          // N*128  (alias: r)
    float* q    = p + (size_t)N * 128;         // N*128  (alias: s)
    float* h1   = q + (size_t)N * 128;         // N*128  (alias: h2, tp)
    float* dinv = h1 + (size_t)N * 128;        // N
    int* rowptr = (int*)(dinv + N);            // N+1
    int* off    = rowptr + (N + 1);            // len+2
    int* colbuf = off + len + 2;               // E
    unsigned* ebuf = (unsigned*)(colbuf + E);  // E
    int* bsum   = (int*)(ebuf + E);            // 32
    uintptr_t up = (uintptr_t)(bsum + 32);
    up = (up + 15) & ~(uintptr_t)15;
    unsigned short* p1h = (unsigned short*)up; // 32768 (128x256)
    unsigned short* p1l = p1h + 32768;
    unsigned short* p2h = p1l + 32768;         // 16384 (128x128)
    unsigned short* p2l = p2h + 16384;
    unsigned short* p3h = p2l + 16384;         // 4096 (64x64)
    unsigned short* p3l = p3h + 4096;

    float* r  = p;                             // N*64
    float* s  = q;                             // N*64
    float* h2 = h1;                            // N*64
    float* tp = h1 + (size_t)N * 64;           // N*64 (= t * dinv)

    float* out = (float*)d_out;

    // --- CSR build (radix by dst) ---
    count_kernel<<<NB, 256, 0, stream>>>(dstp, off, E, NB, BK);
    const int sn = len + 1;
    const int SBs = (sn + 2047) / 2048;
    scan_reduce_kernel<<<SBs, 256, 0, stream>>>(off, bsum, sn);
    scan_offsets_kernel<<<1, 64, 0, stream>>>(bsum, SBs);
    scan_final_kernel<<<SBs, 256, 0, stream>>>(off, bsum, sn);
    partition_kernel<<<NB, 256, 0, stream>>>(srcp, dstp, off, ebuf, E, NB, BK);
    finalize_kernel<<<BK, 256, 0, stream>>>(ebuf, off, colbuf, rowptr, dinv, N, NB, E);

    packw_kernel<<<dim3(64, 5), 256, 0, stream>>>(W1l, W1r, W2l, W2r, Wg,
                                                  p1h, p1l, p2h, p2l, p3h, p3l);

    const int gb = (N + 63) / 64;
    const int nblk16 = (N + 15) / 16;

    gemm_mfma_kernel<128, 256, true><<<gb, 256, 0, stream>>>(x, p1h, p1l, p, q, nullptr, N);
    agg1_sharded_kernel<<<8 * nblk16, 256, 0, stream>>>(p, q, rowptr, colbuf, b1l, h1, N);

    gemm_mfma_kernel<128, 128, true><<<gb, 256, 0, stream>>>(h1, p2h, p2l, r, s, nullptr, N);
    agg2_sharded_kernel<<<4 * nblk16, 256, 0, stream>>>(r, s, rowptr, colbuf, b2l, h2, N);
    softmax64_kernel<<<(N + 3) / 4, 256, 0, stream>>>(h2, N);

    gemm_mfma_kernel<64, 64, false><<<gb, 256, 0, stream>>>(h2, p3h, p3l, tp, nullptr, dinv, N);
    gcn_sharded_kernel<<<4 * nblk16, 256, 0, stream>>>(tp, rowptr, colbuf, dinv, bg, out, N);
}

// Round 8
// 338.580 us; speedup vs baseline: 1.3084x; 1.3084x over previous
//
#include <hip/hip_runtime.h>
#include <math.h>

// ---------------------------------------------------------------------------
// ADSAGE: 2x SAGEConv (mean aggr) + softmax + GCNConv, fp32.
// Aggregate-after-GEMM (mean is linear). GEMMs on matrix cores via
// split-bf16 (3-term). CSR via 2-pass radix sort by dst. Gathers: one wave
// per node, float4 lanes (2 or 4 lane-groups walk edges in parallel), 4
// independent chains -> 64B in flight per lane, shfl_xor cross-group reduce.
// Pipeline:
//   p,q = x @ [W1l|W1r]                          MFMA GEMM K=128
//   h1  = relu(mean(p) + q + b1l)                gather
//   r,s = h1 @ [W2l|W2r]                         MFMA GEMM K=128
//   h2  = softmax(mean(r) + s + b2l)             gather + fused softmax
//   tp  = (h2 @ Wg) * dinv[row]                  MFMA GEMM K=64 + epilogue
//   out = dinv*(sum_j tp[j] + tp[i]) + bg        gather
// ---------------------------------------------------------------------------

typedef __attribute__((ext_vector_type(8))) short bf16x8;
typedef __attribute__((ext_vector_type(4))) float f32x4;

__device__ inline unsigned short f32_bf16_hi(float f) {
    unsigned int u = __builtin_bit_cast(unsigned int, f);
    u = (u + 0x7FFFu + ((u >> 16) & 1u)) >> 16;
    return (unsigned short)u;
}
__device__ inline float bf16_to_f32(unsigned short h) {
    unsigned int u = ((unsigned int)h) << 16;
    return __builtin_bit_cast(float, u);
}

// ----------------------- radix CSR build (by dst) --------------------------
__global__ void count_kernel(const int* __restrict__ dst, int* __restrict__ off,
                             int E, int NB, int BK) {
    __shared__ int hist[256];
    int t = threadIdx.x;
    hist[t] = 0;
    __syncthreads();
    int base = blockIdx.x * 8192;
    for (int i = t; i < 8192; i += 256) {
        int e = base + i;
        if (e < E) atomicAdd(&hist[dst[e] >> 8], 1);
    }
    __syncthreads();
    if (t < BK) off[1 + t * NB + blockIdx.x] = hist[t];
    if (blockIdx.x == 0 && t == 0) off[0] = 0;
}

__global__ void scan_reduce_kernel(const int* __restrict__ data, int* __restrict__ bsum, int n) {
    __shared__ int red[256];
    int t = threadIdx.x;
    int base = blockIdx.x * 2048 + t * 8;
    int s = 0;
    if (base + 8 <= n) {
        int4 a = *(const int4*)(data + base);
        int4 b = *(const int4*)(data + base + 4);
        s = a.x + a.y + a.z + a.w + b.x + b.y + b.z + b.w;
    } else {
        for (int i = 0; i < 8; ++i)
            if (base + i < n) s += data[base + i];
    }
    red[t] = s;
    __syncthreads();
    for (int off = 128; off > 0; off >>= 1) {
        if (t < off) red[t] += red[t + off];
        __syncthreads();
    }
    if (t == 0) bsum[blockIdx.x] = red[0];
}

__global__ void scan_offsets_kernel(int* __restrict__ bsum, int B) {
    if (threadIdx.x == 0 && blockIdx.x == 0) {
        int run = 0;
        for (int i = 0; i < B; ++i) { int v = bsum[i]; bsum[i] = run; run += v; }
    }
}

__global__ void scan_final_kernel(int* __restrict__ data, const int* __restrict__ bsum, int n) {
    __shared__ int tsum[256];
    int t = threadIdx.x;
    int base = blockIdx.x * 2048 + t * 8;
    int v[8];
    int s = 0;
#pragma unroll
    for (int i = 0; i < 8; ++i) {
        v[i] = (base + i < n) ? data[base + i] : 0;
        s += v[i];
    }
    tsum[t] = s;
    for (int off = 1; off < 256; off <<= 1) {
        __syncthreads();
        int u = (t >= off) ? tsum[t - off] : 0;
        __syncthreads();
        tsum[t] += u;
    }
    __syncthreads();
    int run = bsum[blockIdx.x] + tsum[t] - s;
#pragma unroll
    for (int i = 0; i < 8; ++i) {
        run += v[i];
        if (base + i < n) data[base + i] = run;
    }
}

__global__ void partition_kernel(const int* __restrict__ src, const int* __restrict__ dst,
                                 const int* __restrict__ off, unsigned* __restrict__ ebuf,
                                 int E, int NB, int BK) {
    __shared__ int cur[256];
    int t = threadIdx.x;
    if (t < BK) cur[t] = off[t * NB + blockIdx.x];
    __syncthreads();
    int base = blockIdx.x * 8192;
    for (int i = t; i < 8192; i += 256) {
        int e = base + i;
        if (e < E) {
            int d = dst[e];
            int pos = atomicAdd(&cur[d >> 8], 1);
            ebuf[pos] = ((unsigned)src[e] << 8) | (unsigned)(d & 255);
        }
    }
}

__global__ void finalize_kernel(const unsigned* __restrict__ ebuf, const int* __restrict__ off,
                                int* __restrict__ col, int* __restrict__ rowptr,
                                float* __restrict__ dinv, int N, int NB, int E) {
    __shared__ int hist[256], scn[256], cur[256];
    int b = blockIdx.x, t = threadIdx.x;
    int base = off[b * NB];
    int end  = off[(b + 1) * NB];
    int M = end - base;
    hist[t] = 0;
    __syncthreads();
    for (int i = t; i < M; i += 256) atomicAdd(&hist[ebuf[base + i] & 255u], 1);
    __syncthreads();
    scn[t] = hist[t];
    for (int o = 1; o < 256; o <<= 1) {
        __syncthreads();
        int u = (t >= o) ? scn[t - o] : 0;
        __syncthreads();
        scn[t] += u;
    }
    __syncthreads();
    int excl = scn[t] - hist[t];
    int node = b * 256 + t;
    if (node < N) {
        rowptr[node] = base + excl;
        dinv[node] = rsqrtf((float)(hist[t] + 1));
    }
    if (b == 0 && t == 0) rowptr[N] = E;
    cur[t] = base + excl;
    __syncthreads();
    for (int i = t; i < M; i += 256) {
        unsigned w = ebuf[base + i];
        int pos = atomicAdd(&cur[w & 255u], 1);
        col[pos] = (int)(w >> 8);
    }
}

// -------------------------- weight pre-pack --------------------------------
__global__ void packw_kernel(const float* __restrict__ W1l, const float* __restrict__ W1r,
                             const float* __restrict__ W2l, const float* __restrict__ W2r,
                             const float* __restrict__ Wg,
                             unsigned short* __restrict__ p1h, unsigned short* __restrict__ p1l,
                             unsigned short* __restrict__ p2h, unsigned short* __restrict__ p2l,
                             unsigned short* __restrict__ p3h, unsigned short* __restrict__ p3l) {
    int which = blockIdx.y;
    const float* W;
    unsigned short *hi, *lo;
    int K, Mp, colOff, T;
    if (which == 0)      { W = W1l; hi = p1h; lo = p1l; K = 128; Mp = 128; colOff = 0;   T = 16; }
    else if (which == 1) { W = W1r; hi = p1h; lo = p1l; K = 128; Mp = 128; colOff = 128; T = 16; }
    else if (which == 2) { W = W2l; hi = p2h; lo = p2l; K = 128; Mp = 64;  colOff = 0;   T = 8;  }
    else if (which == 3) { W = W2r; hi = p2h; lo = p2l; K = 128; Mp = 64;  colOff = 64;  T = 8;  }
    else                 { W = Wg;  hi = p3h; lo = p3l; K = 64;  Mp = 64;  colOff = 0;   T = 4;  }
    int idx = blockIdx.x * blockDim.x + threadIdx.x;
    if (idx >= K * Mp) return;
    int k = idx / Mp, m = idx % Mp;
    float w = W[(size_t)k * Mp + m];
    int colI = colOff + m;
    int s = k >> 5, kk = k & 31, qq = kk >> 3, j = kk & 7;
    int tt = colI >> 4, n = colI & 15;
    int lane = qq * 16 + n;
    size_t pos = ((size_t)(s * T + tt) * 64 + lane) * 8 + j;
    unsigned short h = f32_bf16_hi(w);
    hi[pos] = h;
    lo[pos] = f32_bf16_hi(w - bf16_to_f32(h));
}

// --------------------------- MFMA GEMM -------------------------------------
template <int K, int M, bool SPLIT>
__launch_bounds__(256)
__global__ void gemm_mfma_kernel(const float* __restrict__ A,
                                 const unsigned short* __restrict__ Whi,
                                 const unsigned short* __restrict__ Wlo,
                                 float* __restrict__ outA, float* __restrict__ outB,
                                 const float* __restrict__ rowScale, int N) {
    constexpr int S = K / 32, T = M / 16, H = M / 2;
    const int lane = threadIdx.x & 63;
    const int wave = threadIdx.x >> 6;
    const int m = lane & 15, q = lane >> 4;
    const int row0 = blockIdx.x * 64 + wave * 16;
    int arow = row0 + m;
    if (arow >= N) arow = N - 1;       // clamp: only pollutes rows we don't store
    const float* ap = A + (size_t)arow * K + q * 8;

    f32x4 acc[T];
#pragma unroll
    for (int t = 0; t < T; ++t) acc[t] = (f32x4)(0.f);

#pragma unroll
    for (int s = 0; s < S; ++s) {
        float av[8];
        *(float4*)(av)     = *(const float4*)(ap + s * 32);
        *(float4*)(av + 4) = *(const float4*)(ap + s * 32 + 4);
        bf16x8 ahi, alo;
#pragma unroll
        for (int i = 0; i < 8; ++i) {
            unsigned short h = f32_bf16_hi(av[i]);
            ahi[i] = (short)h;
            alo[i] = (short)f32_bf16_hi(av[i] - bf16_to_f32(h));
        }
        const int base = s * T * 64 + lane;
        const bf16x8* whp = (const bf16x8*)Whi;
        const bf16x8* wlp = (const bf16x8*)Wlo;
#pragma unroll
        for (int t = 0; t < T; ++t) {
            bf16x8 wh = whp[base + t * 64];
            bf16x8 wl = wlp[base + t * 64];
            acc[t] = __builtin_amdgcn_mfma_f32_16x16x32_bf16(ahi, wh, acc[t], 0, 0, 0);
            acc[t] = __builtin_amdgcn_mfma_f32_16x16x32_bf16(alo, wh, acc[t], 0, 0, 0);
            acc[t] = __builtin_amdgcn_mfma_f32_16x16x32_bf16(ahi, wl, acc[t], 0, 0, 0);
        }
    }

#pragma unroll
    for (int r = 0; r < 4; ++r) {
        int row = row0 + q * 4 + r;
        if (row < N) {
            float sc = rowScale ? rowScale[row] : 1.0f;
#pragma unroll
            for (int t = 0; t < T; ++t) {
                int c = t * 16 + m;
                float v = acc[t][r] * sc;
                if (!SPLIT) {
                    outA[(size_t)row * M + c] = v;
                } else if (c < H) {
                    outA[(size_t)row * H + c] = v;
                } else {
                    outB[(size_t)row * H + (c - H)] = v;
                }
            }
        }
    }
}

// ------------------------------ gathers ------------------------------------
// agg1: wave/node, row=128 floats = 2 groups x 32 lanes x float4.
// 8 edges in flight (2 groups x 4 chains). h1 = relu(mean(p)+q+b1l).
__global__ void agg1_relu_kernel(const float* __restrict__ p, const float* __restrict__ q,
                                 const int* __restrict__ rowptr, const int* __restrict__ col,
                                 const float* __restrict__ b1l,
                                 float* __restrict__ h1, int N) {
    int node = blockIdx.x * 4 + (threadIdx.x >> 6);
    if (node >= N) return;
    const int lane = threadIdx.x & 63;
    const int g = lane >> 5;           // 0..1
    const int fl = lane & 31;
    const int fo = fl * 4;
    int s = rowptr[node], e = rowptr[node + 1];
    float4 a0 = make_float4(0.f,0.f,0.f,0.f), a1 = a0, a2 = a0, a3 = a0;
    for (int base = s; base < e; base += 8) {
        int i0 = base + g, i1 = base + 2 + g, i2 = base + 4 + g, i3 = base + 6 + g;
        if (i0 < e) { float4 v = *(const float4*)(p + (size_t)col[i0] * 128 + fo);
                      a0.x += v.x; a0.y += v.y; a0.z += v.z; a0.w += v.w; }
        if (i1 < e) { float4 v = *(const float4*)(p + (size_t)col[i1] * 128 + fo);
                      a1.x += v.x; a1.y += v.y; a1.z += v.z; a1.w += v.w; }
        if (i2 < e) { float4 v = *(const float4*)(p + (size_t)col[i2] * 128 + fo);
                      a2.x += v.x; a2.y += v.y; a2.z += v.z; a2.w += v.w; }
        if (i3 < e) { float4 v = *(const float4*)(p + (size_t)col[i3] * 128 + fo);
                      a3.x += v.x; a3.y += v.y; a3.z += v.z; a3.w += v.w; }
    }
    float4 acc;
    acc.x = (a0.x + a1.x) + (a2.x + a3.x);
    acc.y = (a0.y + a1.y) + (a2.y + a3.y);
    acc.z = (a0.z + a1.z) + (a2.z + a3.z);
    acc.w = (a0.w + a1.w) + (a2.w + a3.w);
    acc.x += __shfl_xor(acc.x, 32, 64);
    acc.y += __shfl_xor(acc.y, 32, 64);
    acc.z += __shfl_xor(acc.z, 32, 64);
    acc.w += __shfl_xor(acc.w, 32, 64);
    if (g == 0) {
        float inv = 1.0f / fmaxf((float)(e - s), 1.0f);
        float4 qv = *(const float4*)(q + (size_t)node * 128 + fo);
        float4 bv = *(const float4*)(b1l + fo);
        float4 r;
        r.x = fmaxf(acc.x * inv + qv.x + bv.x, 0.f);
        r.y = fmaxf(acc.y * inv + qv.y + bv.y, 0.f);
        r.z = fmaxf(acc.z * inv + qv.z + bv.z, 0.f);
        r.w = fmaxf(acc.w * inv + qv.w + bv.w, 0.f);
        *(float4*)(h1 + (size_t)node * 128 + fo) = r;
    }
}

// agg2+softmax: wave/node, row=64 floats = 4 groups x 16 lanes x float4.
// 16 edges in flight. h2 = softmax(mean(r)+s+b2l).
__global__ void agg2_softmax_kernel(const float* __restrict__ rr, const float* __restrict__ ss,
                                    const int* __restrict__ rowptr, const int* __restrict__ col,
                                    const float* __restrict__ b2l,
                                    float* __restrict__ h2, int N) {
    int node = blockIdx.x * 4 + (threadIdx.x >> 6);
    if (node >= N) return;
    const int lane = threadIdx.x & 63;
    const int g = lane >> 4;           // 0..3
    const int fl = lane & 15;
    const int fo = fl * 4;
    int s = rowptr[node], e = rowptr[node + 1];
    float4 a0 = make_float4(0.f,0.f,0.f,0.f), a1 = a0, a2 = a0, a3 = a0;
    for (int base = s; base < e; base += 16) {
        int i0 = base + g, i1 = base + 4 + g, i2 = base + 8 + g, i3 = base + 12 + g;
        if (i0 < e) { float4 v = *(const float4*)(rr + (size_t)col[i0] * 64 + fo);
                      a0.x += v.x; a0.y += v.y; a0.z += v.z; a0.w += v.w; }
        if (i1 < e) { float4 v = *(const float4*)(rr + (size_t)col[i1] * 64 + fo);
                      a1.x += v.x; a1.y += v.y; a1.z += v.z; a1.w += v.w; }
        if (i2 < e) { float4 v = *(const float4*)(rr + (size_t)col[i2] * 64 + fo);
                      a2.x += v.x; a2.y += v.y; a2.z += v.z; a2.w += v.w; }
        if (i3 < e) { float4 v = *(const float4*)(rr + (size_t)col[i3] * 64 + fo);
                      a3.x += v.x; a3.y += v.y; a3.z += v.z; a3.w += v.w; }
    }
    float4 acc;
    acc.x = (a0.x + a1.x) + (a2.x + a3.x);
    acc.y = (a0.y + a1.y) + (a2.y + a3.y);
    acc.z = (a0.z + a1.z) + (a2.z + a3.z);
    acc.w = (a0.w + a1.w) + (a2.w + a3.w);
#pragma unroll
    for (int o = 16; o < 64; o <<= 1) {
        acc.x += __shfl_xor(acc.x, o, 64);
        acc.y += __shfl_xor(acc.y, o, 64);
        acc.z += __shfl_xor(acc.z, o, 64);
        acc.w += __shfl_xor(acc.w, o, 64);
    }
    if (g == 0) {
        float inv = 1.0f / fmaxf((float)(e - s), 1.0f);
        float4 sv = *(const float4*)(ss + (size_t)node * 64 + fo);
        float4 bv = *(const float4*)(b2l + fo);
        float4 v;
        v.x = acc.x * inv + sv.x + bv.x;
        v.y = acc.y * inv + sv.y + bv.y;
        v.z = acc.z * inv + sv.z + bv.z;
        v.w = acc.w * inv + sv.w + bv.w;
        // softmax across the 64 features held as float4 in 16 lanes
        float mx = fmaxf(fmaxf(v.x, v.y), fmaxf(v.z, v.w));
#pragma unroll
        for (int o = 1; o < 16; o <<= 1) mx = fmaxf(mx, __shfl_xor(mx, o, 64));
        float4 ex;
        ex.x = expf(v.x - mx); ex.y = expf(v.y - mx);
        ex.z = expf(v.z - mx); ex.w = expf(v.w - mx);
        float sm = (ex.x + ex.y) + (ex.z + ex.w);
#pragma unroll
        for (int o = 1; o < 16; o <<= 1) sm += __shfl_xor(sm, o, 64);
        float is = 1.0f / sm;
        float4 r;
        r.x = ex.x * is; r.y = ex.y * is; r.z = ex.z * is; r.w = ex.w * is;
        *(float4*)(h2 + (size_t)node * 64 + fo) = r;
    }
}

// gcn: wave/node, row=64 = 4 groups x 16 lanes x float4, tp = t*dinv.
// out = dinv[i]*(sum_j tp[j] + tp[i]) + bg.
__global__ void gcn_agg_kernel(const float* __restrict__ tp,
                               const int* __restrict__ rowptr, const int* __restrict__ col,
                               const float* __restrict__ dinv, const float* __restrict__ bg,
                               float* __restrict__ out, int N) {
    int node = blockIdx.x * 4 + (threadIdx.x >> 6);
    if (node >= N) return;
    const int lane = threadIdx.x & 63;
    const int g = lane >> 4;
    const int fl = lane & 15;
    const int fo = fl * 4;
    int s = rowptr[node], e = rowptr[node + 1];
    float4 a0 = make_float4(0.f,0.f,0.f,0.f), a1 = a0, a2 = a0, a3 = a0;
    for (int base = s; base < e; base += 16) {
        int i0 = base + g, i1 = base + 4 + g, i2 = base + 8 + g, i3 = base + 12 + g;
        if (i0 < e) { float4 v = *(const float4*)(tp + (size_t)col[i0] * 64 + fo);
                      a0.x += v.x; a0.y += v.y; a0.z += v.z; a0.w += v.w; }
        if (i1 < e) { float4 v = *(const float4*)(tp + (size_t)col[i1] * 64 + fo);
                      a1.x += v.x; a1.y += v.y; a1.z += v.z; a1.w += v.w; }
        if (i2 < e) { float4 v = *(const float4*)(tp + (size_t)col[i2] * 64 + fo);
                      a2.x += v.x; a2.y += v.y; a2.z += v.z; a2.w += v.w; }
        if (i3 < e) { float4 v = *(const float4*)(tp + (size_t)col[i3] * 64 + fo);
                      a3.x += v.x; a3.y += v.y; a3.z += v.z; a3.w += v.w; }
    }
    float4 acc;
    acc.x = (a0.x + a1.x) + (a2.x + a3.x);
    acc.y = (a0.y + a1.y) + (a2.y + a3.y);
    acc.z = (a0.z + a1.z) + (a2.z + a3.z);
    acc.w = (a0.w + a1.w) + (a2.w + a3.w);
#pragma unroll
    for (int o = 16; o < 64; o <<= 1) {
        acc.x += __shfl_xor(acc.x, o, 64);
        acc.y += __shfl_xor(acc.y, o, 64);
        acc.z += __shfl_xor(acc.z, o, 64);
        acc.w += __shfl_xor(acc.w, o, 64);
    }
    if (g == 0) {
        float di = dinv[node];
        float4 self = *(const float4*)(tp + (size_t)node * 64 + fo);
        float4 bv = *(const float4*)(bg + fo);
        float4 r;
        r.x = (acc.x + self.x) * di + bv.x;
        r.y = (acc.y + self.y) * di + bv.y;
        r.z = (acc.z + self.z) * di + bv.z;
        r.w = (acc.w + self.w) * di + bv.w;
        *(float4*)(out + (size_t)node * 64 + fo) = r;
    }
}

extern "C" void kernel_launch(void* const* d_in, const int* in_sizes, int n_in,
                              void* d_out, int out_size, void* d_ws, size_t ws_size,
                              hipStream_t stream) {
    const float* x = (const float*)d_in[0];
    const int* ei = (const int*)d_in[1];    // int32 per harness conversion
    const float* W1l = (const float*)d_in[2];
    const float* b1l = (const float*)d_in[3];
    const float* W1r = (const float*)d_in[4];
    const float* W2l = (const float*)d_in[5];
    const float* b2l = (const float*)d_in[6];
    const float* W2r = (const float*)d_in[7];
    const float* Wg  = (const float*)d_in[8];
    const float* bg  = (const float*)d_in[9];

    const int N = in_sizes[0] / 128;
    const int E = in_sizes[1] / 2;
    const int* srcp = ei;
    const int* dstp = ei + E;

    const int NB = (E + 8191) / 8192;       // partition blocks
    const int BK = (N + 255) >> 8;          // dst buckets
    const int len = BK * NB;

    // workspace layout
    float* ws = (float*)d_ws;
    float* p    = ws;                          // N*128  (alias: r)
    float* q    = p + (size_t)N * 128;         // N*128  (alias: s)
    float* h1   = q + (size_t)N * 128;         // N*128  (alias: h2, tp)
    float* dinv = h1 + (size_t)N * 128;        // N
    int* rowptr = (int*)(dinv + N);            // N+1
    int* off    = rowptr + (N + 1);            // len+2
    int* colbuf = off + len + 2;               // E
    unsigned* ebuf = (unsigned*)(colbuf + E);  // E
    int* bsum   = (int*)(ebuf + E);            // 32
    uintptr_t up = (uintptr_t)(bsum + 32);
    up = (up + 15) & ~(uintptr_t)15;
    unsigned short* p1h = (unsigned short*)up; // 32768 (128x256)
    unsigned short* p1l = p1h + 32768;
    unsigned short* p2h = p1l + 32768;         // 16384 (128x128)
    unsigned short* p2l = p2h + 16384;
    unsigned short* p3h = p2l + 16384;         // 4096 (64x64)
    unsigned short* p3l = p3h + 4096;

    float* r  = p;                             // N*64
    float* s  = q;                             // N*64
    float* h2 = h1;                            // N*64
    float* tp = h1 + (size_t)N * 64;           // N*64 (= t * dinv)

    float* out = (float*)d_out;

    // --- CSR build (radix by dst) ---
    count_kernel<<<NB, 256, 0, stream>>>(dstp, off, E, NB, BK);
    const int sn = len + 1;
    const int SBs = (sn + 2047) / 2048;
    scan_reduce_kernel<<<SBs, 256, 0, stream>>>(off, bsum, sn);
    scan_offsets_kernel<<<1, 64, 0, stream>>>(bsum, SBs);
    scan_final_kernel<<<SBs, 256, 0, stream>>>(off, bsum, sn);
    partition_kernel<<<NB, 256, 0, stream>>>(srcp, dstp, off, ebuf, E, NB, BK);
    finalize_kernel<<<BK, 256, 0, stream>>>(ebuf, off, colbuf, rowptr, dinv, N, NB, E);

    packw_kernel<<<dim3(64, 5), 256, 0, stream>>>(W1l, W1r, W2l, W2r, Wg,
                                                  p1h, p1l, p2h, p2l, p3h, p3l);

    const int gb = (N + 63) / 64;
    const int ab = (N + 3) / 4;

    gemm_mfma_kernel<128, 256, true><<<gb, 256, 0, stream>>>(x, p1h, p1l, p, q, nullptr, N);
    agg1_relu_kernel<<<ab, 256, 0, stream>>>(p, q, rowptr, colbuf, b1l, h1, N);

    gemm_mfma_kernel<128, 128, true><<<gb, 256, 0, stream>>>(h1, p2h, p2l, r, s, nullptr, N);
    agg2_softmax_kernel<<<ab, 256, 0, stream>>>(r, s, rowptr, colbuf, b2l, h2, N);

    gemm_mfma_kernel<64, 64, false><<<gb, 256, 0, stream>>>(h2, p3h, p3l, tp, nullptr, dinv, N);
    gcn_agg_kernel<<<ab, 256, 0, stream>>>(tp, rowptr, colbuf, dinv, bg, out, N);
}

// Round 9
// 320.212 us; speedup vs baseline: 1.3835x; 1.0574x over previous
//
#include <hip/hip_runtime.h>
#include <hip/hip_fp16.h>
#include <math.h>

// ---------------------------------------------------------------------------
// ADSAGE: 2x SAGEConv (mean aggr) + softmax + GCNConv, fp32.
// Aggregate-after-GEMM (mean is linear). GEMMs on matrix cores via
// split-bf16 (3-term). CSR via 2-pass radix sort by dst.
// Gathered activations (p, r) stored FP16 -> gather traffic halves (the
// agg kernels were pinned at ~188MB L2-miss traffic @ ~3.4TB/s).
// Pipeline:
//   p16,q = x @ [W1l|W1r]                        MFMA GEMM K=128 (p fp16)
//   h1  = relu(mean(p16) + q + b1l)              gather (half2 lanes)
//   r16,s = h1 @ [W2l|W2r]                       MFMA GEMM K=128 (r fp16)
//   h2  = softmax(mean(r16) + s + b2l)           gather + fused softmax
//   tp  = (h2 @ Wg) * dinv[row]                  MFMA GEMM K=64 + epilogue
//   out = dinv*(sum_j tp[j] + tp[i]) + bg        gather (fp32)
// ---------------------------------------------------------------------------

typedef __attribute__((ext_vector_type(8))) short bf16x8;
typedef __attribute__((ext_vector_type(4))) float f32x4;

__device__ inline unsigned short f32_bf16_hi(float f) {
    unsigned int u = __builtin_bit_cast(unsigned int, f);
    u = (u + 0x7FFFu + ((u >> 16) & 1u)) >> 16;
    return (unsigned short)u;
}
__device__ inline float bf16_to_f32(unsigned short h) {
    unsigned int u = ((unsigned int)h) << 16;
    return __builtin_bit_cast(float, u);
}

// ----------------------- radix CSR build (by dst) --------------------------
__global__ void count_kernel(const int* __restrict__ dst, int* __restrict__ off,
                             int E, int NB, int BK) {
    __shared__ int hist[256];
    int t = threadIdx.x;
    hist[t] = 0;
    __syncthreads();
    int base = blockIdx.x * 8192;
    for (int i = t; i < 8192; i += 256) {
        int e = base + i;
        if (e < E) atomicAdd(&hist[dst[e] >> 8], 1);
    }
    __syncthreads();
    if (t < BK) off[1 + t * NB + blockIdx.x] = hist[t];
    if (blockIdx.x == 0 && t == 0) off[0] = 0;
}

__global__ void scan_reduce_kernel(const int* __restrict__ data, int* __restrict__ bsum, int n) {
    __shared__ int red[256];
    int t = threadIdx.x;
    int base = blockIdx.x * 2048 + t * 8;
    int s = 0;
    if (base + 8 <= n) {
        int4 a = *(const int4*)(data + base);
        int4 b = *(const int4*)(data + base + 4);
        s = a.x + a.y + a.z + a.w + b.x + b.y + b.z + b.w;
    } else {
        for (int i = 0; i < 8; ++i)
            if (base + i < n) s += data[base + i];
    }
    red[t] = s;
    __syncthreads();
    for (int off = 128; off > 0; off >>= 1) {
        if (t < off) red[t] += red[t + off];
        __syncthreads();
    }
    if (t == 0) bsum[blockIdx.x] = red[0];
}

__global__ void scan_offsets_kernel(int* __restrict__ bsum, int B) {
    if (threadIdx.x == 0 && blockIdx.x == 0) {
        int run = 0;
        for (int i = 0; i < B; ++i) { int v = bsum[i]; bsum[i] = run; run += v; }
    }
}

__global__ void scan_final_kernel(int* __restrict__ data, const int* __restrict__ bsum, int n) {
    __shared__ int tsum[256];
    int t = threadIdx.x;
    int base = blockIdx.x * 2048 + t * 8;
    int v[8];
    int s = 0;
#pragma unroll
    for (int i = 0; i < 8; ++i) {
        v[i] = (base + i < n) ? data[base + i] : 0;
        s += v[i];
    }
    tsum[t] = s;
    for (int off = 1; off < 256; off <<= 1) {
        __syncthreads();
        int u = (t >= off) ? tsum[t - off] : 0;
        __syncthreads();
        tsum[t] += u;
    }
    __syncthreads();
    int run = bsum[blockIdx.x] + tsum[t] - s;
#pragma unroll
    for (int i = 0; i < 8; ++i) {
        run += v[i];
        if (base + i < n) data[base + i] = run;
    }
}

__global__ void partition_kernel(const int* __restrict__ src, const int* __restrict__ dst,
                                 const int* __restrict__ off, unsigned* __restrict__ ebuf,
                                 int E, int NB, int BK) {
    __shared__ int cur[256];
    int t = threadIdx.x;
    if (t < BK) cur[t] = off[t * NB + blockIdx.x];
    __syncthreads();
    int base = blockIdx.x * 8192;
    for (int i = t; i < 8192; i += 256) {
        int e = base + i;
        if (e < E) {
            int d = dst[e];
            int pos = atomicAdd(&cur[d >> 8], 1);
            ebuf[pos] = ((unsigned)src[e] << 8) | (unsigned)(d & 255);
        }
    }
}

__global__ void finalize_kernel(const unsigned* __restrict__ ebuf, const int* __restrict__ off,
                                int* __restrict__ col, int* __restrict__ rowptr,
                                float* __restrict__ dinv, int N, int NB, int E) {
    __shared__ int hist[256], scn[256], cur[256];
    int b = blockIdx.x, t = threadIdx.x;
    int base = off[b * NB];
    int end  = off[(b + 1) * NB];
    int M = end - base;
    hist[t] = 0;
    __syncthreads();
    for (int i = t; i < M; i += 256) atomicAdd(&hist[ebuf[base + i] & 255u], 1);
    __syncthreads();
    scn[t] = hist[t];
    for (int o = 1; o < 256; o <<= 1) {
        __syncthreads();
        int u = (t >= o) ? scn[t - o] : 0;
        __syncthreads();
        scn[t] += u;
    }
    __syncthreads();
    int excl = scn[t] - hist[t];
    int node = b * 256 + t;
    if (node < N) {
        rowptr[node] = base + excl;
        dinv[node] = rsqrtf((float)(hist[t] + 1));
    }
    if (b == 0 && t == 0) rowptr[N] = E;
    cur[t] = base + excl;
    __syncthreads();
    for (int i = t; i < M; i += 256) {
        unsigned w = ebuf[base + i];
        int pos = atomicAdd(&cur[w & 255u], 1);
        col[pos] = (int)(w >> 8);
    }
}

// -------------------------- weight pre-pack --------------------------------
__global__ void packw_kernel(const float* __restrict__ W1l, const float* __restrict__ W1r,
                             const float* __restrict__ W2l, const float* __restrict__ W2r,
                             const float* __restrict__ Wg,
                             unsigned short* __restrict__ p1h, unsigned short* __restrict__ p1l,
                             unsigned short* __restrict__ p2h, unsigned short* __restrict__ p2l,
                             unsigned short* __restrict__ p3h, unsigned short* __restrict__ p3l) {
    int which = blockIdx.y;
    const float* W;
    unsigned short *hi, *lo;
    int K, Mp, colOff, T;
    if (which == 0)      { W = W1l; hi = p1h; lo = p1l; K = 128; Mp = 128; colOff = 0;   T = 16; }
    else if (which == 1) { W = W1r; hi = p1h; lo = p1l; K = 128; Mp = 128; colOff = 128; T = 16; }
    else if (which == 2) { W = W2l; hi = p2h; lo = p2l; K = 128; Mp = 64;  colOff = 0;   T = 8;  }
    else if (which == 3) { W = W2r; hi = p2h; lo = p2l; K = 128; Mp = 64;  colOff = 64;  T = 8;  }
    else                 { W = Wg;  hi = p3h; lo = p3l; K = 64;  Mp = 64;  colOff = 0;   T = 4;  }
    int idx = blockIdx.x * blockDim.x + threadIdx.x;
    if (idx >= K * Mp) return;
    int k = idx / Mp, m = idx % Mp;
    float w = W[(size_t)k * Mp + m];
    int colI = colOff + m;
    int s = k >> 5, kk = k & 31, qq = kk >> 3, j = kk & 7;
    int tt = colI >> 4, n = colI & 15;
    int lane = qq * 16 + n;
    size_t pos = ((size_t)(s * T + tt) * 64 + lane) * 8 + j;
    unsigned short h = f32_bf16_hi(w);
    hi[pos] = h;
    lo[pos] = f32_bf16_hi(w - bf16_to_f32(h));
}

// --------------------------- MFMA GEMM -------------------------------------
// out = A[N,K] @ Wpacked[K,M]. SPLIT: cols [0,M/2)->outA, [M/2,M)->outB.
// A16: outA is fp16 (__half), outB fp32. rowScale: scale output row.
template <int K, int M, bool SPLIT, bool A16>
__launch_bounds__(256)
__global__ void gemm_mfma_kernel(const float* __restrict__ A,
                                 const unsigned short* __restrict__ Whi,
                                 const unsigned short* __restrict__ Wlo,
                                 void* __restrict__ outAv, float* __restrict__ outB,
                                 const float* __restrict__ rowScale, int N) {
    constexpr int S = K / 32, T = M / 16, H = M / 2;
    const int lane = threadIdx.x & 63;
    const int wave = threadIdx.x >> 6;
    const int m = lane & 15, q = lane >> 4;
    const int row0 = blockIdx.x * 64 + wave * 16;
    int arow = row0 + m;
    if (arow >= N) arow = N - 1;       // clamp: only pollutes rows we don't store
    const float* ap = A + (size_t)arow * K + q * 8;

    f32x4 acc[T];
#pragma unroll
    for (int t = 0; t < T; ++t) acc[t] = (f32x4)(0.f);

#pragma unroll
    for (int s = 0; s < S; ++s) {
        float av[8];
        *(float4*)(av)     = *(const float4*)(ap + s * 32);
        *(float4*)(av + 4) = *(const float4*)(ap + s * 32 + 4);
        bf16x8 ahi, alo;
#pragma unroll
        for (int i = 0; i < 8; ++i) {
            unsigned short h = f32_bf16_hi(av[i]);
            ahi[i] = (short)h;
            alo[i] = (short)f32_bf16_hi(av[i] - bf16_to_f32(h));
        }
        const int base = s * T * 64 + lane;
        const bf16x8* whp = (const bf16x8*)Whi;
        const bf16x8* wlp = (const bf16x8*)Wlo;
#pragma unroll
        for (int t = 0; t < T; ++t) {
            bf16x8 wh = whp[base + t * 64];
            bf16x8 wl = wlp[base + t * 64];
            acc[t] = __builtin_amdgcn_mfma_f32_16x16x32_bf16(ahi, wh, acc[t], 0, 0, 0);
            acc[t] = __builtin_amdgcn_mfma_f32_16x16x32_bf16(alo, wh, acc[t], 0, 0, 0);
            acc[t] = __builtin_amdgcn_mfma_f32_16x16x32_bf16(ahi, wl, acc[t], 0, 0, 0);
        }
    }

#pragma unroll
    for (int r = 0; r < 4; ++r) {
        int row = row0 + q * 4 + r;
        if (row < N) {
            float sc = rowScale ? rowScale[row] : 1.0f;
#pragma unroll
            for (int t = 0; t < T; ++t) {
                int c = t * 16 + m;
                float v = acc[t][r] * sc;
                if (!SPLIT) {
                    ((float*)outAv)[(size_t)row * M + c] = v;
                } else if (c < H) {
                    if (A16) ((__half*)outAv)[(size_t)row * H + c] = __float2half(v);
                    else     ((float*)outAv)[(size_t)row * H + c] = v;
                } else {
                    outB[(size_t)row * H + (c - H)] = v;
                }
            }
        }
    }
}

// ------------------------------ gathers ------------------------------------
// agg1: wave/node; lane owns features [lane*2, lane*2+1]; p fp16 (row 128h =
// 256B/edge); 4 independent edge chains. h1 = relu(mean(p)+q+b1l), fp32 out.
__global__ void agg1_relu_kernel(const __half* __restrict__ p, const float* __restrict__ q,
                                 const int* __restrict__ rowptr, const int* __restrict__ col,
                                 const float* __restrict__ b1l,
                                 float* __restrict__ h1, int N) {
    int node = blockIdx.x * 4 + (threadIdx.x >> 6);
    if (node >= N) return;
    const int lane = threadIdx.x & 63;
    int s = rowptr[node], e = rowptr[node + 1];
    float ax = 0.f, ay = 0.f, bx = 0.f, by = 0.f;
    float cx = 0.f, cy = 0.f, dx = 0.f, dy = 0.f;
    int pp = s;
    for (; pp + 4 <= e; pp += 4) {
        int j0 = col[pp], j1 = col[pp + 1], j2 = col[pp + 2], j3 = col[pp + 3];
        float2 v0 = __half22float2(*(const __half2*)(p + (size_t)j0 * 128 + lane * 2));
        float2 v1 = __half22float2(*(const __half2*)(p + (size_t)j1 * 128 + lane * 2));
        float2 v2 = __half22float2(*(const __half2*)(p + (size_t)j2 * 128 + lane * 2));
        float2 v3 = __half22float2(*(const __half2*)(p + (size_t)j3 * 128 + lane * 2));
        ax += v0.x; ay += v0.y; bx += v1.x; by += v1.y;
        cx += v2.x; cy += v2.y; dx += v3.x; dy += v3.y;
    }
    for (; pp < e; ++pp) {
        int j0 = col[pp];
        float2 v0 = __half22float2(*(const __half2*)(p + (size_t)j0 * 128 + lane * 2));
        ax += v0.x; ay += v0.y;
    }
    ax = (ax + bx) + (cx + dx);
    ay = (ay + by) + (cy + dy);
    float inv = 1.0f / fmaxf((float)(e - s), 1.0f);
    float2 qv = *(const float2*)(q + (size_t)node * 128 + lane * 2);
    float2 bv = *(const float2*)(b1l + lane * 2);
    float2 r;
    r.x = fmaxf(ax * inv + qv.x + bv.x, 0.f);
    r.y = fmaxf(ay * inv + qv.y + bv.y, 0.f);
    *(float2*)(h1 + (size_t)node * 128 + lane * 2) = r;
}

// agg2+softmax: wave/node; lane owns feature [lane]; r fp16 (row 64h =
// 128B/edge); 4 chains; fused softmax across the 64 lanes. h2 fp32.
__global__ void agg2_softmax_kernel(const __half* __restrict__ rr, const float* __restrict__ ss,
                                    const int* __restrict__ rowptr, const int* __restrict__ col,
                                    const float* __restrict__ b2l,
                                    float* __restrict__ h2, int N) {
    int node = blockIdx.x * 4 + (threadIdx.x >> 6);
    if (node >= N) return;
    int lane = threadIdx.x & 63;
    int s = rowptr[node], e = rowptr[node + 1];
    float a0 = 0.f, a1 = 0.f, a2 = 0.f, a3 = 0.f;
    int p = s;
    for (; p + 4 <= e; p += 4) {
        int j0 = col[p], j1 = col[p + 1], j2 = col[p + 2], j3 = col[p + 3];
        a0 += __half2float(rr[(size_t)j0 * 64 + lane]);
        a1 += __half2float(rr[(size_t)j1 * 64 + lane]);
        a2 += __half2float(rr[(size_t)j2 * 64 + lane]);
        a3 += __half2float(rr[(size_t)j3 * 64 + lane]);
    }
    for (; p < e; ++p) a0 += __half2float(rr[(size_t)col[p] * 64 + lane]);
    float acc = (a0 + a1) + (a2 + a3);
    float inv = 1.0f / fmaxf((float)(e - s), 1.0f);
    float v = acc * inv + ss[(size_t)node * 64 + lane] + b2l[lane];
    float mx = v;
#pragma unroll
    for (int o = 32; o > 0; o >>= 1) mx = fmaxf(mx, __shfl_xor(mx, o, 64));
    float ex = expf(v - mx);
    float ssum = ex;
#pragma unroll
    for (int o = 32; o > 0; o >>= 1) ssum += __shfl_xor(ssum, o, 64);
    h2[(size_t)node * 64 + lane] = ex / ssum;
}

// gcn: wave/node; lane owns feature [lane]; tp fp32 (pre-scaled by dinv in
// gemm3 epilogue); 4 chains. out = dinv[i]*(sum_j tp[j] + tp[i]) + bg.
__global__ void gcn_agg_kernel(const float* __restrict__ tp,
                               const int* __restrict__ rowptr, const int* __restrict__ col,
                               const float* __restrict__ dinv, const float* __restrict__ bg,
                               float* __restrict__ out, int N) {
    int node = blockIdx.x * 4 + (threadIdx.x >> 6);
    if (node >= N) return;
    int lane = threadIdx.x & 63;
    int s = rowptr[node], e = rowptr[node + 1];
    float a0 = 0.f, a1 = 0.f, a2 = 0.f, a3 = 0.f;
    int p = s;
    for (; p + 4 <= e; p += 4) {
        int j0 = col[p], j1 = col[p + 1], j2 = col[p + 2], j3 = col[p + 3];
        a0 += tp[(size_t)j0 * 64 + lane];
        a1 += tp[(size_t)j1 * 64 + lane];
        a2 += tp[(size_t)j2 * 64 + lane];
        a3 += tp[(size_t)j3 * 64 + lane];
    }
    for (; p < e; ++p) a0 += tp[(size_t)col[p] * 64 + lane];
    float acc = (a0 + a1) + (a2 + a3);
    float di = dinv[node];
    out[(size_t)node * 64 + lane] =
        (acc + tp[(size_t)node * 64 + lane]) * di + bg[lane];
}

extern "C" void kernel_launch(void* const* d_in, const int* in_sizes, int n_in,
                              void* d_out, int out_size, void* d_ws, size_t ws_size,
                              hipStream_t stream) {
    const float* x = (const float*)d_in[0];
    const int* ei = (const int*)d_in[1];    // int32 per harness conversion
    const float* W1l = (const float*)d_in[2];
    const float* b1l = (const float*)d_in[3];
    const float* W1r = (const float*)d_in[4];
    const float* W2l = (const float*)d_in[5];
    const float* b2l = (const float*)d_in[6];
    const float* W2r = (const float*)d_in[7];
    const float* Wg  = (const float*)d_in[8];
    const float* bg  = (const float*)d_in[9];

    const int N = in_sizes[0] / 128;
    const int E = in_sizes[1] / 2;
    const int* srcp = ei;
    const int* dstp = ei + E;

    const int NB = (E + 8191) / 8192;       // partition blocks
    const int BK = (N + 255) >> 8;          // dst buckets
    const int len = BK * NB;

    // workspace layout
    float* ws = (float*)d_ws;
    float* q    = ws;                          // N*128 fp32 (alias: s)
    float* h1   = q + (size_t)N * 128;         // N*128 fp32 (alias: h2)
    float* tp   = h1 + (size_t)N * 128;        // N*64 fp32
    float* dinv = tp + (size_t)N * 64;         // N
    __half* p16 = (__half*)(dinv + N);         // N*128 half (alias: r16)
    int* rowptr = (int*)(p16 + (size_t)N * 128); // N+1
    int* off    = rowptr + (N + 1);            // len+2
    int* colbuf = off + len + 2;               // E
    unsigned* ebuf = (unsigned*)(colbuf + E);  // E
    int* bsum   = (int*)(ebuf + E);            // 32
    uintptr_t up = (uintptr_t)(bsum + 32);
    up = (up + 15) & ~(uintptr_t)15;
    unsigned short* p1h = (unsigned short*)up; // 32768 (128x256)
    unsigned short* p1l = p1h + 32768;
    unsigned short* p2h = p1l + 32768;         // 16384 (128x128)
    unsigned short* p2l = p2h + 16384;
    unsigned short* p3h = p2l + 16384;         // 4096 (64x64)
    unsigned short* p3l = p3h + 4096;

    __half* r16 = p16;                         // N*64 half (p16 dead after agg1)
    float* s  = q;                             // N*64
    float* h2 = h1;                            // N*64

    float* out = (float*)d_out;

    // --- CSR build (radix by dst) ---
    count_kernel<<<NB, 256, 0, stream>>>(dstp, off, E, NB, BK);
    const int sn = len + 1;
    const int SBs = (sn + 2047) / 2048;
    scan_reduce_kernel<<<SBs, 256, 0, stream>>>(off, bsum, sn);
    scan_offsets_kernel<<<1, 64, 0, stream>>>(bsum, SBs);
    scan_final_kernel<<<SBs, 256, 0, stream>>>(off, bsum, sn);
    partition_kernel<<<NB, 256, 0, stream>>>(srcp, dstp, off, ebuf, E, NB, BK);
    finalize_kernel<<<BK, 256, 0, stream>>>(ebuf, off, colbuf, rowptr, dinv, N, NB, E);

    packw_kernel<<<dim3(64, 5), 256, 0, stream>>>(W1l, W1r, W2l, W2r, Wg,
                                                  p1h, p1l, p2h, p2l, p3h, p3l);

    const int gb = (N + 63) / 64;
    const int ab = (N + 3) / 4;

    gemm_mfma_kernel<128, 256, true, true><<<gb, 256, 0, stream>>>(
        x, p1h, p1l, (void*)p16, q, nullptr, N);
    agg1_relu_kernel<<<ab, 256, 0, stream>>>(p16, q, rowptr, colbuf, b1l, h1, N);

    gemm_mfma_kernel<128, 128, true, true><<<gb, 256, 0, stream>>>(
        h1, p2h, p2l, (void*)r16, s, nullptr, N);
    agg2_softmax_kernel<<<ab, 256, 0, stream>>>(r16, s, rowptr, colbuf, b2l, h2, N);

    gemm_mfma_kernel<64, 64, false, false><<<gb, 256, 0, stream>>>(
        h2, p3h, p3l, (void*)tp, nullptr, dinv, N);
    gcn_agg_kernel<<<ab, 256, 0, stream>>>(tp, rowptr, colbuf, dinv, bg, out, N);
}